// Round 3
// baseline (203.679 us; speedup 1.0000x reference)
//
#include <hip/hip_runtime.h>

#define D_    2560
#define NH_   8
#define NKV_  4
#define HD_   256
#define FFN_  10240
#define QD_   2048
#define CTX_  4096
#define EPSF  1e-6f
#define LCHUNKS 16
#define LCHUNK  256

__device__ __forceinline__ float wave_red_sum(float v) {
#pragma unroll
    for (int o = 32; o > 0; o >>= 1) v += __shfl_down(v, o, 64);
    return v;
}

__device__ __forceinline__ float block_red_sum(float v) {
    __shared__ float s[4];
    __shared__ float tot;
    int lane = threadIdx.x & 63, w = threadIdx.x >> 6;
    v = wave_red_sum(v);
    if (lane == 0) s[w] = v;
    __syncthreads();
    if (threadIdx.x == 0) tot = s[0] + s[1] + s[2] + s[3];
    __syncthreads();
    return tot;
}

__device__ __forceinline__ float block_red_max(float v) {
    __shared__ float s[4];
    __shared__ float tot;
    int lane = threadIdx.x & 63, w = threadIdx.x >> 6;
#pragma unroll
    for (int o = 32; o > 0; o >>= 1) v = fmaxf(v, __shfl_down(v, o, 64));
    if (lane == 0) s[w] = v;
    __syncthreads();
    if (threadIdx.x == 0) tot = fmaxf(fmaxf(s[0], s[1]), fmaxf(s[2], s[3]));
    __syncthreads();
    return tot;
}

// ---- streaming GEMV partials: copy-shaped memory stream ----
// W row-major rows x (SLOTS*256) cols. Wave-iteration `it` covers row it/SLOTS,
// column-chunk (it%SLOTS)*256 .. +256 (64 float4, one per lane).
// part[it] = partial dot. Persistent grid-stride, no barriers, no atomics.
template <int SLOTS>
__global__ __launch_bounds__(256) void k_stream(const float* __restrict__ W,
                                                const float* __restrict__ x,
                                                float* __restrict__ part,
                                                int total) {
    const float4* W4 = (const float4*)W;
    const float4* X4 = (const float4*)x;
    int lane = threadIdx.x & 63;
    int gw = (blockIdx.x * 256 + threadIdx.x) >> 6;
    int nw = (gridDim.x * 256) >> 6;
#pragma unroll 4
    for (int it = gw; it < total; it += nw) {
        int slot = it % SLOTS;
        float4 w = W4[(size_t)it * 64 + lane];
        float4 xx = X4[slot * 64 + lane];
        float p = w.x * xx.x + w.y * xx.y + w.z * xx.z + w.w * xx.w;
        p = wave_red_sum(p);
        if (lane == 0) part[it] = p;
    }
}

// fused two-matrix version (Wg then Wu), rows each, same x.
template <int SLOTS>
__global__ __launch_bounds__(256) void k_stream2(const float* __restrict__ Wa,
                                                 const float* __restrict__ Wb,
                                                 const float* __restrict__ x,
                                                 float* __restrict__ part,
                                                 int rows) {
    const float4* X4 = (const float4*)x;
    int lane = threadIdx.x & 63;
    int gw = (blockIdx.x * 256 + threadIdx.x) >> 6;
    int nw = (gridDim.x * 256) >> 6;
    int half = rows * SLOTS;
    int total = 2 * half;
#pragma unroll 4
    for (int it = gw; it < total; it += nw) {
        int slot = it % SLOTS;
        int itm = (it < half) ? it : it - half;
        const float4* W4 = (const float4*)((it < half) ? Wa : Wb);
        float4 w = W4[(size_t)itm * 64 + lane];
        float4 xx = X4[slot * 64 + lane];
        float p = w.x * xx.x + w.y * xx.y + w.z * xx.z + w.w * xx.w;
        p = wave_red_sum(p);
        if (lane == 0) part[it] = p;
    }
}

// out1 = (res?) res + rms(a)*(1+w1);  a[i] = sum_{s<slots} apart[i*slots+s]
// optionally out2 = rms(out1)*(1+w2).  one block, 256 threads.
__global__ void k_res_rms(const float* __restrict__ res,
                          const float* __restrict__ apart, int slots,
                          const float* __restrict__ w1, float* __restrict__ out1,
                          const float* __restrict__ w2, float* __restrict__ out2) {
    const int K = D_ / 256;
    int t = threadIdx.x;
    float va[K];
    float ss = 0.f;
#pragma unroll
    for (int k = 0; k < K; k++) {
        int i = t + k * 256;
        float v = 0.f;
        for (int s = 0; s < slots; s++) v += apart[(size_t)i * slots + s];
        va[k] = v;
        ss += v * v;
    }
    float tot = block_red_sum(ss);
    float rs = rsqrtf(tot / (float)D_ + EPSF);
    float vo[K];
    float ss2 = 0.f;
#pragma unroll
    for (int k = 0; k < K; k++) {
        int i = t + k * 256;
        float r = res ? res[i] : 0.f;
        vo[k] = r + va[k] * rs * (1.f + w1[i]);
        out1[i] = vo[k];
        ss2 += vo[k] * vo[k];
    }
    if (out2) {
        float tot2 = block_red_sum(ss2);
        float rs2 = rsqrtf(tot2 / (float)D_ + EPSF);
#pragma unroll
        for (int k = 0; k < K; k++) {
            int i = t + k * 256;
            out2[i] = vo[k] * rs2 * (1.f + w2[i]);
        }
    }
}

// per-head q-norm + RoPE, summing Wq partials (10 slots).  grid=NH_, block=HD_
__global__ void k_qnorm_rope(const float* __restrict__ part_q,
                             const float* __restrict__ cosv,
                             const float* __restrict__ sinv,
                             float* __restrict__ qout) {
    __shared__ float qn[HD_];
    int h = blockIdx.x, d = threadIdx.x;
    int r = h * HD_ + d;
    float v = 0.f;
#pragma unroll
    for (int s = 0; s < 10; s++) v += part_q[(size_t)r * 10 + s];
    float tot = block_red_sum(v * v);
    float rs = rsqrtf(tot / (float)HD_ + EPSF);
    float n = v * rs;
    qn[d] = n;
    __syncthreads();
    float rot = (d < HD_ / 2) ? -qn[d + HD_ / 2] : qn[d - HD_ / 2];
    qout[h * HD_ + d] = n * cosv[d] + rot * sinv[d];
}

// scores for both q-heads of one kv head.  grid=(NKV_, LCHUNKS), block=256
__global__ void k_scores(const float* __restrict__ Kc, const float* __restrict__ q,
                         const float* __restrict__ mask, float* __restrict__ s) {
    int kvh = blockIdx.x, chunk = blockIdx.y;
    int lane = threadIdx.x & 63, w = threadIdx.x >> 6;
    int h0 = 2 * kvh, h1 = h0 + 1;
    const float4* q4 = (const float4*)q;
    float4 q0 = q4[h0 * 64 + lane];
    float4 q1 = q4[h1 * 64 + lane];
    int lbase = chunk * LCHUNK + w * 64;
    for (int i = 0; i < 64; i++) {
        int l = lbase + i;
        const float4* Kr = (const float4*)(Kc + ((size_t)kvh * CTX_ + l) * HD_);
        float4 kk = Kr[lane];
        float d0 = kk.x * q0.x + kk.y * q0.y + kk.z * q0.z + kk.w * q0.w;
        float d1 = kk.x * q1.x + kk.y * q1.y + kk.z * q1.z + kk.w * q1.w;
#pragma unroll
        for (int o = 32; o > 0; o >>= 1) {
            d0 += __shfl_down(d0, o, 64);
            d1 += __shfl_down(d1, o, 64);
        }
        if (lane == 0) {
            float m = mask[l];
            s[(size_t)h0 * CTX_ + l] = d0 + m;
            s[(size_t)h1 * CTX_ + l] = d1 + m;
        }
    }
}

// in-place softmax over CTX_ per head.  grid=NH_, block=256
__global__ void k_softmax(float* __restrict__ s) {
    int h = blockIdx.x, t = threadIdx.x;
    float* sh = s + (size_t)h * CTX_;
    float m = -1e30f;
    for (int l = t; l < CTX_; l += 256) m = fmaxf(m, sh[l]);
    m = block_red_max(m);
    float sum = 0.f;
    for (int l = t; l < CTX_; l += 256) {
        float e = expf(sh[l] - m);
        sh[l] = e;
        sum += e;
    }
    sum = block_red_sum(sum);
    float inv = 1.f / sum;
    for (int l = t; l < CTX_; l += 256) sh[l] *= inv;
}

// weighted V partials: V read once per kv head, used by both q heads.
__global__ void k_wv(const float* __restrict__ V, const float* __restrict__ p,
                     float* __restrict__ part) {
    int kvh = blockIdx.x, chunk = blockIdx.y, d = threadIdx.x;
    int h0 = 2 * kvh, h1 = h0 + 1;
    __shared__ float p0[LCHUNK], p1[LCHUNK];
    int l0 = chunk * LCHUNK;
    p0[d] = p[(size_t)h0 * CTX_ + l0 + d];
    p1[d] = p[(size_t)h1 * CTX_ + l0 + d];
    __syncthreads();
    const float* Vb = V + ((size_t)kvh * CTX_ + l0) * HD_;
    float a0 = 0.f, a1 = 0.f;
    for (int li = 0; li < LCHUNK; li++) {
        float v = Vb[(size_t)li * HD_ + d];
        a0 += p0[li] * v;
        a1 += p1[li] * v;
    }
    part[((h0 * LCHUNKS) + chunk) * HD_ + d] = a0;
    part[((h1 * LCHUNKS) + chunk) * HD_ + d] = a1;
}

__global__ void k_reduce_a(const float* __restrict__ part, float* __restrict__ a) {
    int h = blockIdx.x, d = threadIdx.x;
    float s = 0.f;
#pragma unroll
    for (int c = 0; c < LCHUNKS; c++) s += part[((h * LCHUNKS) + c) * HD_ + d];
    a[h * HD_ + d] = s;
}

// gu[i] = gelu_tanh(sum g partials) * (sum u partials).  grid=FFN/256
__global__ void k_gelu_fuse(const float* __restrict__ part_g,
                            const float* __restrict__ part_u,
                            float* __restrict__ gu) {
    int i = blockIdx.x * 256 + threadIdx.x;
    float g = 0.f, u = 0.f;
#pragma unroll
    for (int s = 0; s < 10; s++) {
        g += part_g[(size_t)i * 10 + s];
        u += part_u[(size_t)i * 10 + s];
    }
    float t = tanhf(0.7978845608028654f * (g + 0.044715f * g * g * g));
    gu[i] = 0.5f * g * (1.f + t) * u;
}

// ffn[r] = sum of 40 Wd partials.  grid=D_/256
__global__ void k_reduce_ffn(const float* __restrict__ part_d, float* __restrict__ ffn) {
    int r = blockIdx.x * 256 + threadIdx.x;
    float s = 0.f;
#pragma unroll
    for (int k = 0; k < 40; k++) s += part_d[(size_t)r * 40 + k];
    ffn[r] = s;
}

extern "C" void kernel_launch(void* const* d_in, const int* in_sizes, int n_in,
                              void* d_out, int out_size, void* d_ws, size_t ws_size,
                              hipStream_t stream) {
    const float* x     = (const float*)d_in[0];
    const float* cosv  = (const float*)d_in[1];
    const float* sinv  = (const float*)d_in[2];
    const float* mask  = (const float*)d_in[3];
    const float* cK    = (const float*)d_in[4];
    const float* cV    = (const float*)d_in[5];
    const float* w_in  = (const float*)d_in[7];
    const float* w_pa  = (const float*)d_in[8];
    const float* w_pf  = (const float*)d_in[9];
    const float* w_pff = (const float*)d_in[10];
    const float* Wq    = (const float*)d_in[11];
    const float* Wo    = (const float*)d_in[12];
    const float* Wg    = (const float*)d_in[13];
    const float* Wu    = (const float*)d_in[14];
    const float* Wd    = (const float*)d_in[15];

    float* ws    = (float*)d_ws;
    float* h     = ws;            // 2560
    float* q     = ws + 2560;     // 2048
    float* sc    = ws + 4608;     // 32768
    float* pwv   = ws + 37376;    // 32768
    float* a     = ws + 70144;    // 2048
    float* x2    = ws + 72192;    // 2560
    float* h2    = ws + 74752;    // 2560
    float* gu    = ws + 77312;    // 10240
    float* ffn   = ws + 87552;    // 2560
    float* A     = ws + 90112;    // 204800 partial arena
    float* partq = A;             // 20480 (dead after qnorm_rope)
    float* parto = A;             // 20480 (dead after res_rms #2)
    float* partg = A;             // 102400
    float* partu = A + 102400;    // 102400
    float* partd = A;             // 102400 (after gelu_fuse consumed g/u)
    float* out   = (float*)d_out;

    const int SB = 2048;  // streaming grid blocks (8192 waves persistent)

    // h = rmsnorm(x, w_in)
    k_res_rms<<<1, 256, 0, stream>>>(nullptr, x, 1, w_in, h, nullptr, nullptr);
    // qraw partials = h @ Wq.T   (2048 rows, 10 slots)
    k_stream<10><<<SB, 256, 0, stream>>>(Wq, h, partq, QD_ * 10);
    // q = rope(qnorm(sum partials))
    k_qnorm_rope<<<NH_, HD_, 0, stream>>>(partq, cosv, sinv, q);
    // attention
    k_scores<<<dim3(NKV_, LCHUNKS), 256, 0, stream>>>(cK, q, mask, sc);
    k_softmax<<<NH_, 256, 0, stream>>>(sc);
    k_wv<<<dim3(NKV_, LCHUNKS), HD_, 0, stream>>>(cV, sc, pwv);
    k_reduce_a<<<NH_, HD_, 0, stream>>>(pwv, a);
    // ao partials = a @ Wo.T   (2560 rows, 8 slots)
    k_stream<8><<<SB, 256, 0, stream>>>(Wo, a, parto, D_ * 8);
    // x2 = x + rms(ao)*(1+w_pa);  h2 = rms(x2)*(1+w_pf)
    k_res_rms<<<1, 256, 0, stream>>>(x, parto, 8, w_pa, x2, w_pf, h2);
    // g/u partials = h2 @ {Wg,Wu}.T  (2x10240 rows, 10 slots)
    k_stream2<10><<<SB, 256, 0, stream>>>(Wg, Wu, h2, partg, FFN_);
    k_gelu_fuse<<<FFN_ / 256, 256, 0, stream>>>(partg, partu, gu);
    // ffn partials = gu @ Wd.T  (2560 rows, 40 slots)
    k_stream<40><<<SB, 256, 0, stream>>>(Wd, gu, partd, D_ * 40);
    k_reduce_ffn<<<D_ / 256, 256, 0, stream>>>(partd, ffn);
    // out = x2 + rms(ffn)*(1+w_pff)
    k_res_rms<<<1, 256, 0, stream>>>(x2, ffn, 1, w_pff, out, nullptr, nullptr);
}